// Round 2
// baseline (4832.402 us; speedup 1.0000x reference)
//
#include <hip/hip_runtime.h>
#include <hip/hip_fp16.h>

#define B_ 64
#define M_ 512
#define N_ 512
#define D_ 128
constexpr float EPS_ = 0.05f;
constexpr float SHIFT_ = 1.0f;   // K' = exp((SHIFT - D)/EPS): keeps fp16 range happy
constexpr int NIT_ = 200;

#define NWG_ 8                   // workgroups per batch
#define ROWS_ (M_ / NWG_)        // 64 rows per WG
#define RPW_ (ROWS_ / 8)         // 8 rows per wave (8 waves per WG)

// ---------------------------------------------------------------------------
// Row norms: xn[b,i] = sum_d x^2, yn[b,j] = sum_d y^2. One wave per row.
__global__ __launch_bounds__(256) void wmd_norms(const float* __restrict__ x,
                                                 const float* __restrict__ y,
                                                 float* __restrict__ xn,
                                                 float* __restrict__ yn) {
    int gw = (int)((blockIdx.x * blockDim.x + threadIdx.x) >> 6);
    int l = threadIdx.x & 63;
    const float* src; float* dst; int row;
    if (gw < B_ * M_) { src = x; dst = xn; row = gw; }
    else              { src = y; dst = yn; row = gw - B_ * M_; }
    float2 a = ((const float2*)(src + (size_t)row * D_))[l];
    float s = a.x * a.x + a.y * a.y;
#pragma unroll
    for (int off = 32; off; off >>= 1) s += __shfl_xor(s, off);
    if (l == 0) dst[row] = s;
}

// ---------------------------------------------------------------------------
// Build K'[b,i,j] = clamp(exp((SHIFT - D_ij)/EPS)) in fp16.
__global__ __launch_bounds__(256) void wmd_build_k(const float* __restrict__ x,
                                                   const float* __restrict__ y,
                                                   const float* __restrict__ xn,
                                                   const float* __restrict__ yn,
                                                   __half* __restrict__ Kp) {
    int b = blockIdx.z, it = blockIdx.y, jt = blockIdx.x;
    __shared__ float xs[32][129];
    __shared__ float ys[32][129];
    const float4* xb = (const float4*)(x + ((size_t)b * M_ + it * 32) * D_);
    const float4* yb = (const float4*)(y + ((size_t)b * N_ + jt * 32) * D_);
    int t = threadIdx.x;
#pragma unroll
    for (int k = 0; k < 4; ++k) {
        int idx = t + k * 256;
        int r = idx >> 5, c = (idx & 31) * 4;
        float4 vx = xb[idx];
        float4 vy = yb[idx];
        xs[r][c] = vx.x; xs[r][c + 1] = vx.y; xs[r][c + 2] = vx.z; xs[r][c + 3] = vx.w;
        ys[r][c] = vy.x; ys[r][c + 1] = vy.y; ys[r][c + 2] = vy.z; ys[r][c + 3] = vy.w;
    }
    __syncthreads();
    int ti = t >> 5, tj = t & 31;
    float a0 = 0.f, a1 = 0.f, a2 = 0.f, a3 = 0.f;
    for (int d = 0; d < D_; ++d) {
        float yv = ys[tj][d];
        a0 += xs[ti][d] * yv;
        a1 += xs[ti + 8][d] * yv;
        a2 += xs[ti + 16][d] * yv;
        a3 += xs[ti + 24][d] * yv;
    }
    float ynj = yn[(size_t)b * N_ + jt * 32 + tj];
    float accs[4] = {a0, a1, a2, a3};
#pragma unroll
    for (int k = 0; k < 4; ++k) {
        int gi = it * 32 + ti + 8 * k;
        float sq = (xn[(size_t)b * M_ + gi] + ynj - 2.0f * accs[k]) * (1.0f / D_);
        float Dv = sqrtf(fmaxf(sq, 1e-12f));
        float kv = expf((SHIFT_ - Dv) * (1.0f / EPS_));
        kv = fmaxf(kv, 1e-7f);
        Kp[((size_t)b * M_ + gi) * N_ + jt * 32 + tj] = __float2half(kv);
    }
}

// ---------------------------------------------------------------------------
// Persistent Sinkhorn, 8 WGs per batch (512 threads each).
// WG g owns rows [g*64, g*64+64). Per iteration: row dots -> u, column
// partials -> own global slot (double-buffered), device-scope barrier,
// all WGs rebuild v redundantly. K' read once per WG per iteration (L2).
__global__ __launch_bounds__(512, 4) void wmd_sinkhorn(const __half* __restrict__ K,
                                                       float* __restrict__ colpart, // [2][B_][NWG_][N_]
                                                       int* __restrict__ cnt,       // [B_]
                                                       float* __restrict__ wmd) {
    int blk = blockIdx.x;        // blk = g*64 + b  -> same XCD for all g of batch b
    int b = blk & 63;
    int g = blk >> 6;
    const __half* Kb = K + ((size_t)b * M_ + g * ROWS_) * N_;
    __shared__ float mrg[8][N_];
    __shared__ float u_s[ROWS_];
    __shared__ float v_s[N_];
    __shared__ float wsum[8];
    int t = threadIdx.x, w = t >> 6, l = t & 63;
    const float pmarg = 1.0f / M_, qmarg = 1.0f / N_;
    float vreg[8];
#pragma unroll
    for (int e = 0; e < 8; ++e) vreg[e] = 1.0f;   // v0 = 1

#pragma unroll 1
    for (int it = 0; it < NIT_; ++it) {
        float ca[8] = {0.f, 0.f, 0.f, 0.f, 0.f, 0.f, 0.f, 0.f};
#pragma unroll
        for (int r = 0; r < RPW_; ++r) {
            int i = w * RPW_ + r;
            uint4 kq = *(const uint4*)(Kb + (size_t)i * N_ + l * 8);
            const __half2* h2 = (const __half2*)&kq;
            float2 f0 = __half22float2(h2[0]);
            float2 f1 = __half22float2(h2[1]);
            float2 f2 = __half22float2(h2[2]);
            float2 f3 = __half22float2(h2[3]);
            float d0 = f0.x * vreg[0] + f0.y * vreg[1];
            float d1 = f1.x * vreg[2] + f1.y * vreg[3];
            float d2 = f2.x * vreg[4] + f2.y * vreg[5];
            float d3 = f3.x * vreg[6] + f3.y * vreg[7];
            float dot = (d0 + d1) + (d2 + d3);
#pragma unroll
            for (int off = 32; off; off >>= 1) dot += __shfl_xor(dot, off);
            float u = pmarg * __builtin_amdgcn_rcpf(dot);
            if (l == 0) u_s[i] = u;
            ca[0] += f0.x * u; ca[1] += f0.y * u; ca[2] += f1.x * u; ca[3] += f1.y * u;
            ca[4] += f2.x * u; ca[5] += f2.y * u; ca[6] += f3.x * u; ca[7] += f3.y * u;
        }
        *(float4*)&mrg[w][l * 8]     = make_float4(ca[0], ca[1], ca[2], ca[3]);
        *(float4*)&mrg[w][l * 8 + 4] = make_float4(ca[4], ca[5], ca[6], ca[7]);
        __syncthreads();
        // intra-WG merge -> own global slot (t indexes all 512 cols)
        {
            float s = 0.f;
#pragma unroll
            for (int ww = 0; ww < 8; ++ww) s += mrg[ww][t];
            __hip_atomic_store(&colpart[(((size_t)(it & 1) * B_ + b) * NWG_ + g) * N_ + t], s,
                               __ATOMIC_RELAXED, __HIP_MEMORY_SCOPE_AGENT);
        }
        __syncthreads();   // all colpart stores drained (vmcnt(0) before barrier)
        if (t == 0) {
            __hip_atomic_fetch_add(&cnt[b], 1, __ATOMIC_RELEASE, __HIP_MEMORY_SCOPE_AGENT);
            int target = NWG_ * (it + 1);
            while (__hip_atomic_load(&cnt[b], __ATOMIC_ACQUIRE, __HIP_MEMORY_SCOPE_AGENT) < target)
                __builtin_amdgcn_s_sleep(1);
        }
        __syncthreads();
        // rebuild v (redundant in every WG): thread t owns column t
        {
            const float* cp = colpart + ((size_t)(it & 1) * B_ + b) * NWG_ * N_;
            float s = 0.f;
#pragma unroll
            for (int gg = 0; gg < NWG_; ++gg)
                s += __hip_atomic_load(&cp[gg * N_ + t], __ATOMIC_RELAXED, __HIP_MEMORY_SCOPE_AGENT);
            v_s[t] = qmarg * __builtin_amdgcn_rcpf(s);
        }
        __syncthreads();
        float4 va = *(const float4*)&v_s[l * 8];
        float4 vb = *(const float4*)&v_s[l * 8 + 4];
        vreg[0] = va.x; vreg[1] = va.y; vreg[2] = va.z; vreg[3] = va.w;
        vreg[4] = vb.x; vreg[5] = vb.y; vreg[6] = vb.z; vreg[7] = vb.w;
    }

    // Final: partial of sum_ij u_i K'_ij v_j * D_ij,  D_ij = SHIFT - EPS*ln(K'_ij)
    float acc = 0.0f;
#pragma unroll
    for (int r = 0; r < RPW_; ++r) {
        int i = w * RPW_ + r;
        uint4 kq = *(const uint4*)(Kb + (size_t)i * N_ + l * 8);
        const __half2* h2 = (const __half2*)&kq;
        float2 f0 = __half22float2(h2[0]);
        float2 f1 = __half22float2(h2[1]);
        float2 f2 = __half22float2(h2[2]);
        float2 f3 = __half22float2(h2[3]);
        float kf[8] = {f0.x, f0.y, f1.x, f1.y, f2.x, f2.y, f3.x, f3.y};
        float u = u_s[i];
#pragma unroll
        for (int e = 0; e < 8; ++e) {
            float Dv = SHIFT_ - EPS_ * __logf(kf[e]);
            acc += (u * kf[e] * vreg[e]) * Dv;
        }
    }
#pragma unroll
    for (int off = 32; off; off >>= 1) acc += __shfl_xor(acc, off);
    if (l == 0) wsum[w] = acc;
    __syncthreads();
    if (t == 0) {
        float s = 0.f;
#pragma unroll
        for (int ww = 0; ww < 8; ++ww) s += wsum[ww];
        atomicAdd(&wmd[b], s);
    }
}

// ---------------------------------------------------------------------------
__global__ void wmd_mse(const float* __restrict__ wmd, const float* __restrict__ labels,
                        float* __restrict__ out) {
    int l = threadIdx.x;
    float d = wmd[l] - labels[l];
    d = d * d;
#pragma unroll
    for (int off = 32; off; off >>= 1) d += __shfl_xor(d, off);
    if (l == 0) out[0] = d * (1.0f / B_);
}

// ---------------------------------------------------------------------------
extern "C" void kernel_launch(void* const* d_in, const int* in_sizes, int n_in,
                              void* d_out, int out_size, void* d_ws, size_t ws_size,
                              hipStream_t stream) {
    const float* x = (const float*)d_in[0];
    const float* y = (const float*)d_in[1];
    const float* labels = (const float*)d_in[2];
    float* out = (float*)d_out;

    char* ws = (char*)d_ws;
    __half* K = (__half*)ws;                                            // 32 MiB
    size_t off = (size_t)B_ * M_ * N_ * sizeof(__half);
    float* xn = (float*)(ws + off);        off += (size_t)B_ * M_ * sizeof(float);
    float* yn = (float*)(ws + off);        off += (size_t)B_ * N_ * sizeof(float);
    float* wmd = (float*)(ws + off);       off += B_ * sizeof(float);
    int* cnt = (int*)(ws + off);           off += B_ * sizeof(int);
    float* colpart = (float*)(ws + off);   // 2*B_*NWG_*N_ floats = 2 MiB

    hipMemsetAsync(wmd, 0, B_ * sizeof(float) + B_ * sizeof(int), stream); // wmd + cnt

    wmd_norms<<<(B_ * (M_ + N_)) / 4, 256, 0, stream>>>(x, y, xn, yn);
    wmd_build_k<<<dim3(N_ / 32, M_ / 32, B_), 256, 0, stream>>>(x, y, xn, yn, K);
    wmd_sinkhorn<<<B_ * NWG_, 512, 0, stream>>>(K, colpart, cnt, wmd);
    wmd_mse<<<1, 64, 0, stream>>>(wmd, labels, out);
}

// Round 3
// 1403.549 us; speedup vs baseline: 3.4430x; 3.4430x over previous
//
#include <hip/hip_runtime.h>
#include <hip/hip_fp16.h>

#define B_ 64
#define M_ 512
#define N_ 512
#define D_ 128
constexpr float EPS_ = 0.05f;
constexpr float SHIFT_ = 1.0f;   // K' = exp((SHIFT - D)/EPS): keeps fp16 range happy
constexpr int NIT_ = 200;

typedef _Float16 h2 __attribute__((ext_vector_type(2)));

__device__ __forceinline__ h2 u2h(unsigned x) { return __builtin_bit_cast(h2, x); }
__device__ __forceinline__ unsigned h2u(h2 x) { return __builtin_bit_cast(unsigned, x); }

__device__ __forceinline__ float fdot2_(h2 a, h2 b, float c) {
#if __has_builtin(__builtin_amdgcn_fdot2)
    return __builtin_amdgcn_fdot2(a, b, c, false);
#else
    float2 af = __half22float2(__builtin_bit_cast(__half2, a));
    float2 bf = __half22float2(__builtin_bit_cast(__half2, b));
    return fmaf(af.x, bf.x, fmaf(af.y, bf.y, c));
#endif
}

// ---------------------------------------------------------------------------
// Row norms: xn[b,i] = sum_d x^2, yn[b,j] = sum_d y^2. One wave per row.
__global__ __launch_bounds__(256) void wmd_norms(const float* __restrict__ x,
                                                 const float* __restrict__ y,
                                                 float* __restrict__ xn,
                                                 float* __restrict__ yn) {
    int gw = (int)((blockIdx.x * blockDim.x + threadIdx.x) >> 6);
    int l = threadIdx.x & 63;
    const float* src; float* dst; int row;
    if (gw < B_ * M_) { src = x; dst = xn; row = gw; }
    else              { src = y; dst = yn; row = gw - B_ * M_; }
    float2 a = ((const float2*)(src + (size_t)row * D_))[l];
    float s = a.x * a.x + a.y * a.y;
#pragma unroll
    for (int off = 32; off; off >>= 1) s += __shfl_xor(s, off);
    if (l == 0) dst[row] = s;
}

// ---------------------------------------------------------------------------
// Build K'[b,i,j] = clamp(exp((SHIFT - D_ij)/EPS)) in fp16.
__global__ __launch_bounds__(256) void wmd_build_k(const float* __restrict__ x,
                                                   const float* __restrict__ y,
                                                   const float* __restrict__ xn,
                                                   const float* __restrict__ yn,
                                                   __half* __restrict__ Kp) {
    int b = blockIdx.z, it = blockIdx.y, jt = blockIdx.x;
    __shared__ float xs[32][129];
    __shared__ float ys[32][129];
    const float4* xb = (const float4*)(x + ((size_t)b * M_ + it * 32) * D_);
    const float4* yb = (const float4*)(y + ((size_t)b * N_ + jt * 32) * D_);
    int t = threadIdx.x;
#pragma unroll
    for (int k = 0; k < 4; ++k) {
        int idx = t + k * 256;
        int r = idx >> 5, c = (idx & 31) * 4;
        float4 vx = xb[idx];
        float4 vy = yb[idx];
        xs[r][c] = vx.x; xs[r][c + 1] = vx.y; xs[r][c + 2] = vx.z; xs[r][c + 3] = vx.w;
        ys[r][c] = vy.x; ys[r][c + 1] = vy.y; ys[r][c + 2] = vy.z; ys[r][c + 3] = vy.w;
    }
    __syncthreads();
    int ti = t >> 5, tj = t & 31;
    float a0 = 0.f, a1 = 0.f, a2 = 0.f, a3 = 0.f;
    for (int d = 0; d < D_; ++d) {
        float yv = ys[tj][d];
        a0 += xs[ti][d] * yv;
        a1 += xs[ti + 8][d] * yv;
        a2 += xs[ti + 16][d] * yv;
        a3 += xs[ti + 24][d] * yv;
    }
    float ynj = yn[(size_t)b * N_ + jt * 32 + tj];
    float accs[4] = {a0, a1, a2, a3};
#pragma unroll
    for (int k = 0; k < 4; ++k) {
        int gi = it * 32 + ti + 8 * k;
        float sq = (xn[(size_t)b * M_ + gi] + ynj - 2.0f * accs[k]) * (1.0f / D_);
        float Dv = sqrtf(fmaxf(sq, 1e-12f));
        float kv = expf((SHIFT_ - Dv) * (1.0f / EPS_));
        kv = fmaxf(kv, 1e-7f);
        Kp[((size_t)b * M_ + gi) * N_ + jt * 32 + tj] = __float2half(kv);
    }
}

// ---------------------------------------------------------------------------
// Persistent Sinkhorn: 1 WG (16 waves) per batch.
// Layout: 16 lanes per row, 4 rows per wave in flight. Lane l: sub = l&15
// owns cols {sub*8 + 128c + e, c=0..3, e=0..7}; rg = l>>4 is row-in-group.
// Wave w owns rows [w*32, w*32+32) in 8 groups of 4.
// Dot via v_dot2_f32_f16 (f32 acc), col partials via v_pk_fma_f16 (fp16),
// cross-wave merge of 16 fp16 partials in f32 via LDS.
__global__ __launch_bounds__(1024, 4) void wmd_sinkhorn(const __half* __restrict__ K,
                                                        float* __restrict__ wmd) {
    int b = blockIdx.x;
    const __half* Kb = K + (size_t)b * M_ * N_;
    __shared__ __half mrg[16][N_];    // per-wave fp16 column partials
    __shared__ __half v_sh[N_];
    __shared__ float u_s[M_];
    __shared__ float wsum[16];
    int t = threadIdx.x, w = t >> 6, l = t & 63;
    int sub = l & 15, rg = l >> 4;
    const float pmarg = 1.0f / M_, qmarg = 1.0f / N_;

    h2 vh[16];
    _Float16 one = (_Float16)1.0f;
#pragma unroll
    for (int j = 0; j < 16; ++j) vh[j] = (h2){one, one};   // v0 = 1

#pragma unroll 1
    for (int it = 0; it < NIT_; ++it) {
        h2 ca[16];
        _Float16 z = (_Float16)0.0f;
#pragma unroll
        for (int j = 0; j < 16; ++j) ca[j] = (h2){z, z};

#pragma unroll 2
        for (int g = 0; g < 8; ++g) {
            int row = (w << 5) + (g << 2) + rg;
            const __half* rp = Kb + (size_t)row * N_ + sub * 8;
            uint4 kq[4];
#pragma unroll
            for (int c = 0; c < 4; ++c) kq[c] = *(const uint4*)(rp + 128 * c);
            const unsigned* kk = (const unsigned*)kq;
            float d0 = 0.f, d1 = 0.f, d2 = 0.f, d3 = 0.f;
#pragma unroll
            for (int j = 0; j < 4; ++j) {
                d0 = fdot2_(u2h(kk[j]),      vh[j],      d0);
                d1 = fdot2_(u2h(kk[4 + j]),  vh[4 + j],  d1);
                d2 = fdot2_(u2h(kk[8 + j]),  vh[8 + j],  d2);
                d3 = fdot2_(u2h(kk[12 + j]), vh[12 + j], d3);
            }
            float dot = (d0 + d1) + (d2 + d3);
#pragma unroll
            for (int off = 1; off < 16; off <<= 1) dot += __shfl_xor(dot, off);
            float u = pmarg * __builtin_amdgcn_rcpf(dot);
            if (sub == 0) u_s[row] = u;
            _Float16 uf = (_Float16)u;
            h2 uh = (h2){uf, uf};
#pragma unroll
            for (int j = 0; j < 16; ++j) ca[j] = u2h(kk[j]) * uh + ca[j];
        }
        // merge the 4 row-groups within the wave (lanes xor 16, 32)
#pragma unroll
        for (int j = 0; j < 16; ++j) {
            ca[j] = ca[j] + u2h((unsigned)__shfl_xor((int)h2u(ca[j]), 16));
            ca[j] = ca[j] + u2h((unsigned)__shfl_xor((int)h2u(ca[j]), 32));
        }
        if (l < 16) {
#pragma unroll
            for (int c = 0; c < 4; ++c) {
                uint4 pk = {h2u(ca[4 * c]), h2u(ca[4 * c + 1]),
                            h2u(ca[4 * c + 2]), h2u(ca[4 * c + 3])};
                *(uint4*)&mrg[w][sub * 8 + 128 * c] = pk;
            }
        }
        __syncthreads();
        if (t < N_) {
            float s = 0.f;
#pragma unroll
            for (int ww = 0; ww < 16; ++ww) s += __half2float(mrg[ww][t]);
            v_sh[t] = __float2half_rn(qmarg * __builtin_amdgcn_rcpf(s));
        }
        __syncthreads();
#pragma unroll
        for (int c = 0; c < 4; ++c) {
            uint4 vv = *(const uint4*)&v_sh[sub * 8 + 128 * c];
            vh[4 * c]     = u2h(vv.x);
            vh[4 * c + 1] = u2h(vv.y);
            vh[4 * c + 2] = u2h(vv.z);
            vh[4 * c + 3] = u2h(vv.w);
        }
    }

    // Final: wmd_b = sum_ij u_i K'_ij v_j * D_ij,  D_ij = SHIFT - EPS*ln(K'_ij)
    float acc = 0.f;
#pragma unroll 1
    for (int g = 0; g < 8; ++g) {
        int row = (w << 5) + (g << 2) + rg;
        const __half* rp = Kb + (size_t)row * N_ + sub * 8;
        float u = u_s[row];
#pragma unroll
        for (int c = 0; c < 4; ++c) {
            uint4 kq = *(const uint4*)(rp + 128 * c);
            const unsigned* kk = (const unsigned*)&kq;
#pragma unroll
            for (int j = 0; j < 4; ++j) {
                float2 kf = __half22float2(__builtin_bit_cast(__half2, kk[j]));
                float2 vf = __half22float2(__builtin_bit_cast(__half2, h2u(vh[4 * c + j])));
                acc += (u * kf.x * vf.x) * (SHIFT_ - EPS_ * __logf(kf.x));
                acc += (u * kf.y * vf.y) * (SHIFT_ - EPS_ * __logf(kf.y));
            }
        }
    }
#pragma unroll
    for (int off = 1; off < 64; off <<= 1) acc += __shfl_xor(acc, off);
    if (l == 0) wsum[w] = acc;
    __syncthreads();
    if (t == 0) {
        float s = 0.f;
#pragma unroll
        for (int ww = 0; ww < 16; ++ww) s += wsum[ww];
        wmd[b] = s;
    }
}

// ---------------------------------------------------------------------------
__global__ void wmd_mse(const float* __restrict__ wmd, const float* __restrict__ labels,
                        float* __restrict__ out) {
    int l = threadIdx.x;
    float d = wmd[l] - labels[l];
    d = d * d;
#pragma unroll
    for (int off = 32; off; off >>= 1) d += __shfl_xor(d, off);
    if (l == 0) out[0] = d * (1.0f / B_);
}

// ---------------------------------------------------------------------------
extern "C" void kernel_launch(void* const* d_in, const int* in_sizes, int n_in,
                              void* d_out, int out_size, void* d_ws, size_t ws_size,
                              hipStream_t stream) {
    const float* x = (const float*)d_in[0];
    const float* y = (const float*)d_in[1];
    const float* labels = (const float*)d_in[2];
    float* out = (float*)d_out;

    char* ws = (char*)d_ws;
    __half* K = (__half*)ws;                                            // 32 MiB
    size_t off = (size_t)B_ * M_ * N_ * sizeof(__half);
    float* xn = (float*)(ws + off);        off += (size_t)B_ * M_ * sizeof(float);
    float* yn = (float*)(ws + off);        off += (size_t)B_ * N_ * sizeof(float);
    float* wmd = (float*)(ws + off);

    wmd_norms<<<(B_ * (M_ + N_)) / 4, 256, 0, stream>>>(x, y, xn, yn);
    wmd_build_k<<<dim3(N_ / 32, M_ / 32, B_), 256, 0, stream>>>(x, y, xn, yn, K);
    wmd_sinkhorn<<<B_, 1024, 0, stream>>>(K, wmd);
    wmd_mse<<<1, 64, 0, stream>>>(wmd, labels, out);
}

// Round 5
// 1271.380 us; speedup vs baseline: 3.8009x; 1.1040x over previous
//
#include <hip/hip_runtime.h>
#include <hip/hip_fp16.h>

#define B_ 64
#define M_ 512
#define N_ 512
#define D_ 128
constexpr float EPS_ = 0.05f;
constexpr float SHIFT_ = 1.25f;  // K' = exp((SHIFT - D)/EPS) fits fp8 e4m3 [~2e-3 .. 448]
constexpr int NIT_ = 200;

typedef _Float16 h2 __attribute__((ext_vector_type(2)));
typedef float f2 __attribute__((ext_vector_type(2)));

__device__ __forceinline__ unsigned h2u(h2 x) { return __builtin_bit_cast(unsigned, x); }
__device__ __forceinline__ h2 u2h(unsigned x) { return __builtin_bit_cast(h2, x); }

// fp8x2 (bytes 0-1 or 2-3 of w) -> h2, via certain-to-exist builtins
template <bool HI>
__device__ __forceinline__ h2 cvt_h2(unsigned w) {
    f2 f = __builtin_amdgcn_cvt_pk_f32_fp8((int)w, HI);
    return __builtin_bit_cast(h2, __builtin_amdgcn_cvt_pkrtz(f.x, f.y));
}
template <bool HI>
__device__ __forceinline__ f2 cvt_f2(unsigned w) {
    return __builtin_amdgcn_cvt_pk_f32_fp8((int)w, HI);
}

__device__ __forceinline__ float dot2f(h2 a, h2 b, float c) {
#if __has_builtin(__builtin_amdgcn_fdot2)
    return __builtin_amdgcn_fdot2(a, b, c, false);
#else
    return fmaf((float)a.x, (float)b.x, fmaf((float)a.y, (float)b.y, c));
#endif
}

// sum over each 16-lane row via DPP (VALU only, no LDS pipe)
__device__ __forceinline__ float red16(float x) {
    x += __builtin_bit_cast(float, __builtin_amdgcn_mov_dpp(__builtin_bit_cast(int, x), 0xB1, 0xF, 0xF, true));  // quad_perm xor1
    x += __builtin_bit_cast(float, __builtin_amdgcn_mov_dpp(__builtin_bit_cast(int, x), 0x4E, 0xF, 0xF, true));  // quad_perm xor2
    x += __builtin_bit_cast(float, __builtin_amdgcn_mov_dpp(__builtin_bit_cast(int, x), 0x124, 0xF, 0xF, true)); // row_ror:4
    x += __builtin_bit_cast(float, __builtin_amdgcn_mov_dpp(__builtin_bit_cast(int, x), 0x128, 0xF, 0xF, true)); // row_ror:8
    return x;
}

// ---------------------------------------------------------------------------
__global__ __launch_bounds__(256) void wmd_norms(const float* __restrict__ x,
                                                 const float* __restrict__ y,
                                                 float* __restrict__ xn,
                                                 float* __restrict__ yn) {
    int gw = (int)((blockIdx.x * blockDim.x + threadIdx.x) >> 6);
    int l = threadIdx.x & 63;
    const float* src; float* dst; int row;
    if (gw < B_ * M_) { src = x; dst = xn; row = gw; }
    else              { src = y; dst = yn; row = gw - B_ * M_; }
    float2 a = ((const float2*)(src + (size_t)row * D_))[l];
    float s = a.x * a.x + a.y * a.y;
#pragma unroll
    for (int off = 32; off; off >>= 1) s += __shfl_xor(s, off);
    if (l == 0) dst[row] = s;
}

// ---------------------------------------------------------------------------
// K'[b,i,j] = clamp(exp((SHIFT - D_ij)/EPS), 448) in fp8 e4m3 (flush-to-0 tail is fine)
__global__ __launch_bounds__(256) void wmd_build_k(const float* __restrict__ x,
                                                   const float* __restrict__ y,
                                                   const float* __restrict__ xn,
                                                   const float* __restrict__ yn,
                                                   unsigned char* __restrict__ Kp) {
    int b = blockIdx.z, it = blockIdx.y, jt = blockIdx.x;
    __shared__ float xs[32][129];
    __shared__ float ys[32][129];
    const float4* xb = (const float4*)(x + ((size_t)b * M_ + it * 32) * D_);
    const float4* yb = (const float4*)(y + ((size_t)b * N_ + jt * 32) * D_);
    int t = threadIdx.x;
#pragma unroll
    for (int k = 0; k < 4; ++k) {
        int idx = t + k * 256;
        int r = idx >> 5, c = (idx & 31) * 4;
        float4 vx = xb[idx];
        float4 vy = yb[idx];
        xs[r][c] = vx.x; xs[r][c + 1] = vx.y; xs[r][c + 2] = vx.z; xs[r][c + 3] = vx.w;
        ys[r][c] = vy.x; ys[r][c + 1] = vy.y; ys[r][c + 2] = vy.z; ys[r][c + 3] = vy.w;
    }
    __syncthreads();
    int ti = t >> 5, tj = t & 31;
    float a0 = 0.f, a1 = 0.f, a2 = 0.f, a3 = 0.f;
    for (int d = 0; d < D_; ++d) {
        float yv = ys[tj][d];
        a0 += xs[ti][d] * yv;
        a1 += xs[ti + 8][d] * yv;
        a2 += xs[ti + 16][d] * yv;
        a3 += xs[ti + 24][d] * yv;
    }
    float ynj = yn[(size_t)b * N_ + jt * 32 + tj];
    float accs[4] = {a0, a1, a2, a3};
#pragma unroll
    for (int k = 0; k < 4; ++k) {
        int gi = it * 32 + ti + 8 * k;
        float sq = (xn[(size_t)b * M_ + gi] + ynj - 2.0f * accs[k]) * (1.0f / D_);
        float Dv = sqrtf(fmaxf(sq, 1e-12f));
        float kv = fminf(expf((SHIFT_ - Dv) * (1.0f / EPS_)), 448.0f);
        unsigned r8 = (unsigned)__builtin_amdgcn_cvt_pk_fp8_f32(kv, kv, 0, false);
        Kp[((size_t)b * M_ + gi) * N_ + jt * 32 + tj] = (unsigned char)(r8 & 0xff);
    }
}

// ---------------------------------------------------------------------------
// Persistent Sinkhorn: 1 WG (16 waves) per batch; the WHOLE fp8 K tile lives in
// VGPRs (64 per lane). Zero global traffic in the 200-iteration loop.
// Lane l: sub = l&15 owns scalar cols {sub*8 + 128c + e}; rg = l>>4 = row-in-group.
// Wave w owns rows [w*32, w*32+32) in 8 groups of 4 rows.
__global__ __launch_bounds__(1024, 4) void wmd_sinkhorn(const unsigned char* __restrict__ K8,
                                                        float* __restrict__ wmd) {
    int b = blockIdx.x;
    const unsigned char* Kb = K8 + (size_t)b * M_ * N_;
    __shared__ h2 mrg[64][264];   // 64 sub-wave rows of column partials (S=264: %32==8 -> read parts hit distinct banks)
    __shared__ h2 v_sh[256];
    __shared__ float wsum[16];
    int t = threadIdx.x, w = t >> 6, l = t & 63;
    int sub = l & 15, rg = l >> 4;
    const float pmarg = 1.0f / M_;

    // ---- preload K into registers: kr[g*4+c] = 8 fp8 (cols sub*8+128c..+8 of row w*32+g*4+rg)
    uint2 kr[32];
    {
        const unsigned char* base = Kb + ((size_t)(w * 32 + rg) * N_) + sub * 8;
#pragma unroll
        for (int g = 0; g < 8; ++g)
#pragma unroll
            for (int c = 0; c < 4; ++c)
                kr[g * 4 + c] = *(const uint2*)(base + g * 4 * N_ + c * 128);
    }

    h2 vh[16];
    float u_f[8];
    _Float16 one = (_Float16)1.0f;
#pragma unroll
    for (int j = 0; j < 16; ++j) vh[j] = (h2){one, one};  // v0 = 1

#pragma unroll 1
    for (int it = 0; it < NIT_; ++it) {
        h2 ca[16];
        _Float16 z = (_Float16)0.0f;
#pragma unroll
        for (int j = 0; j < 16; ++j) ca[j] = (h2){z, z};

#pragma unroll
        for (int g = 0; g < 8; ++g) {
            float d0 = 0.f, d1 = 0.f, d2 = 0.f, d3 = 0.f;
#pragma unroll
            for (int c = 0; c < 4; ++c) {
                unsigned lo = kr[g * 4 + c].x, hi = kr[g * 4 + c].y;
                d0 = dot2f(cvt_h2<false>(lo), vh[4 * c + 0], d0);
                d1 = dot2f(cvt_h2<true>(lo),  vh[4 * c + 1], d1);
                d2 = dot2f(cvt_h2<false>(hi), vh[4 * c + 2], d2);
                d3 = dot2f(cvt_h2<true>(hi),  vh[4 * c + 3], d3);
            }
            float dot = red16((d0 + d1) + (d2 + d3));
            float rd = __builtin_amdgcn_rcpf(dot);   // = 512*u (scaled u keeps fp16 mid-range)
            u_f[g] = rd;
            _Float16 uf = (_Float16)rd;
            h2 uh = (h2){uf, uf};
#pragma unroll
            for (int c = 0; c < 4; ++c) {
                unsigned lo = kr[g * 4 + c].x, hi = kr[g * 4 + c].y;
                ca[4 * c + 0] = cvt_h2<false>(lo) * uh + ca[4 * c + 0];
                ca[4 * c + 1] = cvt_h2<true>(lo)  * uh + ca[4 * c + 1];
                ca[4 * c + 2] = cvt_h2<false>(hi) * uh + ca[4 * c + 2];
                ca[4 * c + 3] = cvt_h2<true>(hi)  * uh + ca[4 * c + 3];
            }
        }
        // each sub-wave writes its own mrg row (b128, BW-floor bound)
        int mr = (w << 2) + rg;
#pragma unroll
        for (int c = 0; c < 4; ++c) {
            uint4 pk = {h2u(ca[4 * c]), h2u(ca[4 * c + 1]), h2u(ca[4 * c + 2]), h2u(ca[4 * c + 3])};
            *(uint4*)&mrg[mr][sub * 4 + 64 * c] = pk;
        }
        __syncthreads();
        // column merge: wave w owns h2-cols [w*16, w*16+16); part = l>>4 sums rows {4k+part}
        {
            int part = rg, cc = sub;
            int col2 = (w << 4) + cc;
            h2 s0 = (h2){z, z}, s1 = (h2){z, z}, s2 = (h2){z, z}, s3 = (h2){z, z};
#pragma unroll
            for (int k = 0; k < 4; ++k) {
                s0 = s0 + mrg[4 * (4 * k + 0) + part][col2];
                s1 = s1 + mrg[4 * (4 * k + 1) + part][col2];
                s2 = s2 + mrg[4 * (4 * k + 2) + part][col2];
                s3 = s3 + mrg[4 * (4 * k + 3) + part][col2];
            }
            h2 s = (s0 + s1) + (s2 + s3);
            s = s + u2h((unsigned)__builtin_amdgcn_ds_swizzle((int)h2u(s), 0x401F));  // xor16
            s = s + u2h((unsigned)__shfl_xor((int)h2u(s), 32));                       // xor32
            if (l < 16) {
                h2 vv;
                vv.x = (_Float16)__builtin_amdgcn_rcpf((float)s.x);  // v = q*512/colsum_scaled = rcp
                vv.y = (_Float16)__builtin_amdgcn_rcpf((float)s.y);
                v_sh[col2] = vv;
            }
        }
        __syncthreads();
#pragma unroll
        for (int c = 0; c < 4; ++c) {
            uint4 vv = *(const uint4*)&v_sh[sub * 4 + 64 * c];
            vh[4 * c + 0] = u2h(vv.x);
            vh[4 * c + 1] = u2h(vv.y);
            vh[4 * c + 2] = u2h(vv.z);
            vh[4 * c + 3] = u2h(vv.w);
        }
    }

    // Final: wmd_b = sum_ij u_i K_ij v_j * D_ij, D_ij = SHIFT - EPS*ln(K_ij)
    // u_f = 512*u  ->  scale by pmarg at the end. Clamp k before log (flushed zeros).
    float acc = 0.f;
#pragma unroll
    for (int g = 0; g < 8; ++g) {
        float us = u_f[g];
#pragma unroll
        for (int c = 0; c < 4; ++c) {
            unsigned lo = kr[g * 4 + c].x, hi = kr[g * 4 + c].y;
            f2 kp[4] = {cvt_f2<false>(lo), cvt_f2<true>(lo), cvt_f2<false>(hi), cvt_f2<true>(hi)};
#pragma unroll
            for (int j = 0; j < 4; ++j) {
                h2 vhj = vh[4 * c + j];
                float kx = fmaxf(kp[j].x, 1e-9f), ky = fmaxf(kp[j].y, 1e-9f);
                acc += (us * kx * (float)vhj.x) * (SHIFT_ - EPS_ * __logf(kx));
                acc += (us * ky * (float)vhj.y) * (SHIFT_ - EPS_ * __logf(ky));
            }
        }
    }
#pragma unroll
    for (int off = 1; off < 64; off <<= 1) acc += __shfl_xor(acc, off);
    if (l == 0) wsum[w] = acc;
    __syncthreads();
    if (t == 0) {
        float s = 0.f;
#pragma unroll
        for (int ww = 0; ww < 16; ++ww) s += wsum[ww];
        wmd[b] = s * pmarg;
    }
}

// ---------------------------------------------------------------------------
__global__ void wmd_mse(const float* __restrict__ wmd, const float* __restrict__ labels,
                        float* __restrict__ out) {
    int l = threadIdx.x;
    float d = wmd[l] - labels[l];
    d = d * d;
#pragma unroll
    for (int off = 32; off; off >>= 1) d += __shfl_xor(d, off);
    if (l == 0) out[0] = d * (1.0f / B_);
}

// ---------------------------------------------------------------------------
extern "C" void kernel_launch(void* const* d_in, const int* in_sizes, int n_in,
                              void* d_out, int out_size, void* d_ws, size_t ws_size,
                              hipStream_t stream) {
    const float* x = (const float*)d_in[0];
    const float* y = (const float*)d_in[1];
    const float* labels = (const float*)d_in[2];
    float* out = (float*)d_out;

    char* ws = (char*)d_ws;
    unsigned char* K8 = (unsigned char*)ws;                             // 16 MiB
    size_t off = (size_t)B_ * M_ * N_;
    float* xn = (float*)(ws + off);        off += (size_t)B_ * M_ * sizeof(float);
    float* yn = (float*)(ws + off);        off += (size_t)B_ * N_ * sizeof(float);
    float* wmd = (float*)(ws + off);

    wmd_norms<<<(B_ * (M_ + N_)) / 4, 256, 0, stream>>>(x, y, xn, yn);
    wmd_build_k<<<dim3(N_ / 32, M_ / 32, B_), 256, 0, stream>>>(x, y, xn, yn, K8);
    wmd_sinkhorn<<<B_, 1024, 0, stream>>>(K8, wmd);
    wmd_mse<<<1, 64, 0, stream>>>(wmd, labels, out);
}